// Round 3
// baseline (420.053 us; speedup 1.0000x reference)
//
#include <hip/hip_runtime.h>
#include <hip/hip_bf16.h>

#define DIMK 512
#define NROWS 131072
#define BM 128
#define BN 128

typedef __bf16 bf16x8 __attribute__((ext_vector_type(8)));
typedef float f32x4 __attribute__((ext_vector_type(4)));

// bf16 [n][k] transposed weight, written by wprep_kernel each launch.
__device__ __attribute__((aligned(16))) unsigned short g_Wt[DIMK * DIMK];

static __device__ __forceinline__ unsigned short f2bf(float f) {
    unsigned u = __builtin_bit_cast(unsigned, f);
    u += 0x7FFFu + ((u >> 16) & 1u);   // round-to-nearest-even
    return (unsigned short)(u >> 16);
}

static __device__ __forceinline__ unsigned pack2(float a, float b) {
    return (unsigned)f2bf(a) | ((unsigned)f2bf(b) << 16);
}

static __device__ __forceinline__ bf16x8 cvt8(float4 a, float4 b) {
    uint4 u = make_uint4(pack2(a.x, a.y), pack2(a.z, a.w),
                         pack2(b.x, b.y), pack2(b.z, b.w));
    return __builtin_bit_cast(bf16x8, u);
}

// Classify mask dtype at runtime. Reads first 8192 words = 32768 bytes,
// in-bounds for uint8(131072B)/int32(512KB)/int64(1MB) interpretations.
//   mode 0: byte bool   (some word not in {0,1})
//   mode 1: int32 0/1   (~50% of words nonzero)
//   mode 2: int64 0/1   (~25% of words nonzero: odd words all 0)
__global__ void mask_detect(const unsigned int* __restrict__ m, int* __restrict__ mode) {
    __shared__ int s_bad, s_cnt;
    const int t = threadIdx.x;  // 1024
    if (t == 0) { s_bad = 0; s_cnt = 0; }
    __syncthreads();
    int bad = 0, cnt = 0;
#pragma unroll
    for (int i = 0; i < 8; i++) {
        unsigned w = m[t + i * 1024];
        bad |= (w > 1u) ? 1 : 0;
        cnt += (w != 0u) ? 1 : 0;
    }
    atomicOr(&s_bad, bad);
    atomicAdd(&s_cnt, cnt);
    __syncthreads();
    if (t == 0) *mode = s_bad ? 0 : (s_cnt > 3072 ? 1 : 2);
}

// Transpose + convert: W[k][n] fp32 -> g_Wt[n][k] bf16. 64x64 tiles, 64 blocks.
__global__ void wprep_kernel(const float* __restrict__ W) {
    __shared__ float tile[64][65];
    const int bk = blockIdx.x & 7;   // k-tile
    const int bn = blockIdx.x >> 3;  // n-tile
    const int t = threadIdx.x;       // 256
    const int rl = t >> 2;           // 0..63
    const int ch = t & 3;            // 0..3, 16 floats each

    const float* src = W + (bk * 64 + rl) * DIMK + bn * 64 + ch * 16;
    float4 v[4];
#pragma unroll
    for (int i = 0; i < 4; i++) v[i] = reinterpret_cast<const float4*>(src)[i];
#pragma unroll
    for (int i = 0; i < 4; i++) {
        tile[rl][ch * 16 + i * 4 + 0] = v[i].x;
        tile[rl][ch * 16 + i * 4 + 1] = v[i].y;
        tile[rl][ch * 16 + i * 4 + 2] = v[i].z;
        tile[rl][ch * 16 + i * 4 + 3] = v[i].w;
    }
    __syncthreads();

    unsigned outw[8];
#pragma unroll
    for (int i = 0; i < 8; i++)
        outw[i] = pack2(tile[ch * 16 + 2 * i][rl], tile[ch * 16 + 2 * i + 1][rl]);

    unsigned short* dst = g_Wt + (bn * 64 + rl) * DIMK + bk * 64 + ch * 16;
    uint4* d4 = reinterpret_cast<uint4*>(dst);
    d4[0] = make_uint4(outw[0], outw[1], outw[2], outw[3]);
    d4[1] = make_uint4(outw[4], outw[5], outw[6], outw[7]);
}

// GEMM: out[r] = mask[r] ? bf16gemm(x,W)[r] : x[r]
// 128x128 tile, 256 threads = 4 waves (2x2), each wave 64x64.
// No LDS, no barriers: direct global->reg->cvt->MFMA, depth-1 A prefetch.
__global__ __launch_bounds__(256, 3)
void gemm_kernel(const float* __restrict__ X, const void* __restrict__ maskp,
                 const int* __restrict__ modep, float* __restrict__ out) {
    const int md = *modep;

    // XCD-bijective swizzle: 4096 blocks, col-tile fastest so the 4 column
    // tiles of one A row-panel are consecutive logical ids on one XCD.
    const int lid = ((blockIdx.x & 7) << 9) + (blockIdx.x >> 3);
    const int tm = lid >> 2;
    const int tn = lid & 3;
    const long row0 = (long)tm * BM;
    const int col0 = tn * BN;

    const int t = threadIdx.x;
    const int lane = t & 63;
    const int wid = t >> 6;
    const int wr = wid >> 1;
    const int wc = wid & 1;
    const int l15 = lane & 15;
    const int lhi = lane >> 4;

    const long arow_base = row0 + wr * 64;   // + m*16 + (row-within-frag)
    const int brow_base = col0 + wc * 64;    // + n*16 + (col-within-frag)

    // Hoist mask bits for my 16 epilogue rows (latency hides under k-loop).
    unsigned mbits = 0;
    {
        const long r00 = arow_base + lhi * 4;
        if (md == 0) {
            const unsigned char* mp = (const unsigned char*)maskp;
#pragma unroll
            for (int m = 0; m < 4; m++)
#pragma unroll
                for (int j = 0; j < 4; j++)
                    mbits |= (mp[r00 + m * 16 + j] ? 1u : 0u) << (m * 4 + j);
        } else if (md == 1) {
            const int* mp = (const int*)maskp;
#pragma unroll
            for (int m = 0; m < 4; m++)
#pragma unroll
                for (int j = 0; j < 4; j++)
                    mbits |= (mp[r00 + m * 16 + j] ? 1u : 0u) << (m * 4 + j);
        } else {
            const unsigned* mp = (const unsigned*)maskp;
#pragma unroll
            for (int m = 0; m < 4; m++)
#pragma unroll
                for (int j = 0; j < 4; j++)
                    mbits |= (mp[2 * (r00 + m * 16 + j)] ? 1u : 0u) << (m * 4 + j);
        }
    }

    // Per-thread base pointers. A frag: row = m*16 + l15, k = lhi*8 (+kt*32).
    // B frag: Wt row (=out col) = n*16 + l15, k = lhi*8 (+kt*32).
    const float* ap[4];
    const unsigned short* bp[4];
#pragma unroll
    for (int m = 0; m < 4; m++)
        ap[m] = X + (arow_base + m * 16 + l15) * DIMK + lhi * 8;
#pragma unroll
    for (int n = 0; n < 4; n++)
        bp[n] = g_Wt + (long)(brow_base + n * 16 + l15) * DIMK + lhi * 8;

    f32x4 acc[4][4] = {};

    float4 ra[4][2];
#pragma unroll
    for (int m = 0; m < 4; m++) {
        ra[m][0] = *reinterpret_cast<const float4*>(ap[m]);
        ra[m][1] = *reinterpret_cast<const float4*>(ap[m] + 4);
    }

#pragma unroll 2
    for (int kt = 0; kt < 16; kt++) {
        bf16x8 bfr[4], afr[4];
#pragma unroll
        for (int n = 0; n < 4; n++)
            bfr[n] = *reinterpret_cast<const bf16x8*>(bp[n] + kt * 32);
#pragma unroll
        for (int m = 0; m < 4; m++)
            afr[m] = cvt8(ra[m][0], ra[m][1]);
        if (kt < 15) {  // depth-1 prefetch of next A raws (HBM latency hide)
#pragma unroll
            for (int m = 0; m < 4; m++) {
                ra[m][0] = *reinterpret_cast<const float4*>(ap[m] + (kt + 1) * 32);
                ra[m][1] = *reinterpret_cast<const float4*>(ap[m] + (kt + 1) * 32 + 4);
            }
        }
#pragma unroll
        for (int m = 0; m < 4; m++)
#pragma unroll
            for (int n = 0; n < 4; n++)
                acc[m][n] = __builtin_amdgcn_mfma_f32_16x16x32_bf16(
                    afr[m], bfr[n], acc[m][n], 0, 0, 0);
    }

    // Epilogue: C/D layout col = lane&15, row = (lane>>4)*4 + reg.
    // Masked rows: scalar acc stores. Unmasked: float4 row copy (exact fp32).
    const int nb = brow_base;
#pragma unroll
    for (int m = 0; m < 4; m++) {
#pragma unroll
        for (int j = 0; j < 4; j++) {
            const long rg = arow_base + m * 16 + lhi * 4 + j;
            const bool msk = (mbits >> (m * 4 + j)) & 1;
            float* orow = out + rg * DIMK + nb;
            if (msk) {
#pragma unroll
                for (int n = 0; n < 4; n++)
                    orow[n * 16 + l15] = acc[m][n][j];
            } else {
                const float4* xr = reinterpret_cast<const float4*>(X + rg * DIMK + nb);
                reinterpret_cast<float4*>(orow)[l15] = xr[l15];
            }
        }
    }
}

extern "C" void kernel_launch(void* const* d_in, const int* in_sizes, int n_in,
                              void* d_out, int out_size, void* d_ws, size_t ws_size,
                              hipStream_t stream) {
    const float* X = (const float*)d_in[0];
    const void* mask = d_in[1];
    const float* W = (const float*)d_in[2];
    float* out = (float*)d_out;
    int* mode = (int*)d_ws;

    hipLaunchKernelGGL(mask_detect, dim3(1), dim3(1024), 0, stream,
                       (const unsigned int*)mask, mode);
    hipLaunchKernelGGL(wprep_kernel, dim3(64), dim3(256), 0, stream, W);
    hipLaunchKernelGGL(gemm_kernel, dim3(NROWS / BM * (DIMK / BN)), dim3(256), 0, stream,
                       X, mask, mode, out);
}

// Round 4
// 259.826 us; speedup vs baseline: 1.6167x; 1.6167x over previous
//
#include <hip/hip_runtime.h>
#include <hip/hip_bf16.h>

#define DIMK 512
#define NROWS 131072

typedef __bf16 bf16x8 __attribute__((ext_vector_type(8)));
typedef __bf16 bf16x4 __attribute__((ext_vector_type(4)));
typedef float f32x4 __attribute__((ext_vector_type(4)));

// W in MFMA-fragment order: [colblk(32)][kblk(64)][l15(16)][8 k-elems] bf16
__device__ __attribute__((aligned(16))) unsigned short g_Wt2[DIMK * DIMK];
__device__ int g_rows[NROWS];   // [0..nmask) masked rows; [NROWS-ncopy..NROWS) copy rows (reversed)
__device__ int g_cnt[2];        // [0]=nmask, [1]=ncopy

// ---------- mask dtype detection (+ counter reset) ----------
__global__ void mask_detect(const unsigned int* __restrict__ m, int* __restrict__ mode) {
    __shared__ int s_bad, s_cnt;
    const int t = threadIdx.x;  // 1024
    if (t == 0) { s_bad = 0; s_cnt = 0; g_cnt[0] = 0; g_cnt[1] = 0; }
    __syncthreads();
    int bad = 0, cnt = 0;
#pragma unroll
    for (int i = 0; i < 8; i++) {
        unsigned w = m[t + i * 1024];
        bad |= (w > 1u) ? 1 : 0;
        cnt += (w != 0u) ? 1 : 0;
    }
    atomicOr(&s_bad, bad);
    atomicAdd(&s_cnt, cnt);
    __syncthreads();
    if (t == 0) *mode = s_bad ? 0 : (s_cnt > 3072 ? 1 : 2);
}

// ---------- stream compaction: masked rows forward, copy rows backward ----------
__global__ void partition_kernel(const void* __restrict__ maskp,
                                 const int* __restrict__ modep) {
    const int md = *modep;
    const int row = blockIdx.x * 256 + threadIdx.x;
    bool pred;
    if (md == 0)      pred = ((const unsigned char*)maskp)[row] != 0;
    else if (md == 1) pred = ((const int*)maskp)[row] != 0;
    else              pred = ((const unsigned*)maskp)[2l * row] != 0;
    const int lane = threadIdx.x & 63;
    unsigned long long b = __ballot(pred);
    int pre = __popcll(b & ((1ull << lane) - 1ull));
    int cnt = __popcll(b);
    int base = 0;
    if (lane == 0 && cnt) base = atomicAdd(&g_cnt[0], cnt);
    base = __shfl(base, 0);
    if (pred) g_rows[base + pre] = row;
    int base2 = 0;
    if (lane == 0 && cnt < 64) base2 = atomicAdd(&g_cnt[1], 64 - cnt);
    base2 = __shfl(base2, 0);
    if (!pred) g_rows[NROWS - 1 - (base2 + (lane - pre))] = row;
}

// ---------- W[k][n] fp32 -> fragment-ordered bf16 ----------
__global__ void wprep_kernel(const float* __restrict__ W) {
    __shared__ float tile[64][65];
    const int bk = blockIdx.x & 7;   // k-tile
    const int bn = blockIdx.x >> 3;  // n-tile
    const int t = threadIdx.x;       // 256
    const int rl = t >> 2;           // 0..63
    const int ch = t & 3;            // 0..3

    const float* src = W + (bk * 64 + rl) * DIMK + bn * 64 + ch * 16;
    float4 v[4];
#pragma unroll
    for (int i = 0; i < 4; i++) v[i] = reinterpret_cast<const float4*>(src)[i];
#pragma unroll
    for (int i = 0; i < 4; i++) {
        tile[rl][ch * 16 + i * 4 + 0] = v[i].x;
        tile[rl][ch * 16 + i * 4 + 1] = v[i].y;
        tile[rl][ch * 16 + i * 4 + 2] = v[i].z;
        tile[rl][ch * 16 + i * 4 + 3] = v[i].w;
    }
    __syncthreads();

    // col = bn*64+rl, k = bk*64 + ch*16 + (0..15) -> bf16 pairs
    unsigned short o[16];
#pragma unroll
    for (int i = 0; i < 16; i++) {
        float f = tile[ch * 16 + i][rl];
        unsigned u = __builtin_bit_cast(unsigned, f);
        u += 0x7FFFu + ((u >> 16) & 1u);
        o[i] = (unsigned short)(u >> 16);
    }
    const int colblk = bn * 4 + (rl >> 4);
    const int kblk = bk * 8 + ch * 2;
    unsigned short* dst = g_Wt2 + colblk * 8192 + kblk * 128 + (rl & 15) * 8;
    *reinterpret_cast<uint4*>(dst) = *reinterpret_cast<uint4*>(&o[0]);
    *reinterpret_cast<uint4*>(dst + 128) = *reinterpret_cast<uint4*>(&o[8]);
}

// ---------- fused: gemm on masked rows + copy of unmasked rows ----------
__global__ __launch_bounds__(256)
void main_kernel(const float* __restrict__ X, float* __restrict__ out) {
    __shared__ __attribute__((aligned(16))) unsigned short Abuf[2][128 * 64];
    __shared__ int rlist[128];

    const int bid = blockIdx.x;
    const int role = (bid >> 3) & 1;               // period-16 interleave: XCD-balanced
    const int idx8 = ((bid >> 4) << 3) | (bid & 7);
    const int t = threadIdx.x;
    const int lane = t & 63;

    if (role == 1) {
        // -------- copy role: 32 unmasked rows per block, 1 wave per row --------
        const int ncopy = g_cnt[1];
        const int c = idx8;
        if (c * 32 >= ncopy) return;
        const int w = t >> 6;
        int rws[8];
#pragma unroll
        for (int i = 0; i < 8; i++) {
            int pos = c * 32 + w * 8 + i;
            rws[i] = (pos < ncopy) ? g_rows[NROWS - 1 - pos] : -1;
        }
#pragma unroll
        for (int i = 0; i < 8; i++) {
            if (rws[i] >= 0) {
                const float4* s = reinterpret_cast<const float4*>(X + (long)rws[i] * DIMK);
                float4* d = reinterpret_cast<float4*>(out + (long)rws[i] * DIMK);
                float4 v0 = s[lane], v1 = s[lane + 64];
                d[lane] = v0;
                d[lane + 64] = v1;
            }
        }
        return;
    }

    // -------- gemm role: 128 masked rows x 128 cols --------
    const int g = idx8;                 // 0..4095
    const int tm = g >> 2, tn = g & 3;
    const int nmask = g_cnt[0];
    if (tm * 128 >= nmask) return;

    if (t < 128) {
        int pos = tm * 128 + t;
        rlist[t] = g_rows[pos < nmask ? pos : 0];
    }
    __syncthreads();

    const int wid = t >> 6, wr = wid >> 1, wc = wid & 1;
    const int l15 = lane & 15, lhi = lane >> 4;

    // staging: thread covers rows rb_+p*32 (p<4), float4 k-chunks {q, q+8} per row
    const int q = t & 7;
    const int rb_ = t >> 3;
    const float* ap[4];
#pragma unroll
    for (int p = 0; p < 4; p++)
        ap[p] = X + (long)rlist[rb_ + p * 32] * DIMK + q * 4;

    // B frag base: elems = colblk*8192 + (kt*8+s*4+lhi)*128 + l15*8
    const unsigned short* bbase = g_Wt2 + (tn * 8 + wc * 4) * 8192 + lhi * 128 + l15 * 8;

    f32x4 acc[4][4] = {};
    float4 ra[4][2];
    bf16x8 bB[4][2];

    // prologue: raw A(0)
#pragma unroll
    for (int p = 0; p < 4; p++) {
        ra[p][0] = *reinterpret_cast<const float4*>(ap[p]);
        ra[p][1] = *reinterpret_cast<const float4*>(ap[p] + 32);
    }
    {   // stage(0)
        char* Aw = reinterpret_cast<char*>(Abuf[0]);
#pragma unroll
        for (int p = 0; p < 4; p++) {
            const int row = rb_ + p * 32;
#pragma unroll
            for (int h = 0; h < 2; h++) {
                const int f = q + 8 * h;
                float4 a = ra[p][h];
                bf16x4 c4;
                c4[0] = (__bf16)a.x; c4[1] = (__bf16)a.y;
                c4[2] = (__bf16)a.z; c4[3] = (__bf16)a.w;
                *reinterpret_cast<bf16x4*>(
                    Aw + row * 128 + (((f >> 1) ^ (row & 7)) << 4) + (f & 1) * 8) = c4;
            }
        }
    }
    // issue B(0) then ra(1): FIFO keeps younger HBM loads behind B waits
#pragma unroll
    for (int n = 0; n < 4; n++)
#pragma unroll
        for (int s = 0; s < 2; s++)
            bB[n][s] = *reinterpret_cast<const bf16x8*>(bbase + n * 8192 + s * 512);
#pragma unroll
    for (int p = 0; p < 4; p++) {
        ra[p][0] = *reinterpret_cast<const float4*>(ap[p] + 64);
        ra[p][1] = *reinterpret_cast<const float4*>(ap[p] + 64 + 32);
    }

#pragma unroll
    for (int kt = 0; kt < 8; kt++) {
        // raw barrier: lgkm drain only — vmcnt prefetches stay in flight (T3/T4)
        asm volatile("s_waitcnt lgkmcnt(0)" ::: "memory");
        __builtin_amdgcn_s_barrier();
        __builtin_amdgcn_sched_barrier(0);

        const char* Ar = reinterpret_cast<const char*>(Abuf[kt & 1]);
#pragma unroll
        for (int s = 0; s < 2; s++) {
            bf16x8 afr[4];
#pragma unroll
            for (int m = 0; m < 4; m++) {
                const int row = wr * 64 + m * 16 + l15;
                afr[m] = *reinterpret_cast<const bf16x8*>(
                    Ar + row * 128 + ((((s << 2) + lhi) ^ (row & 7)) << 4));
            }
#pragma unroll
            for (int m = 0; m < 4; m++)
#pragma unroll
                for (int n = 0; n < 4; n++)
                    acc[m][n] = __builtin_amdgcn_mfma_f32_16x16x32_bf16(
                        afr[m], bB[n][s], acc[m][n], 0, 0, 0);
        }
        if (kt < 7) {
            // cvt + swizzled LDS write of ra(kt+1) (arrived: in flight one full phase)
            char* Aw = reinterpret_cast<char*>(Abuf[(kt + 1) & 1]);
#pragma unroll
            for (int p = 0; p < 4; p++) {
                const int row = rb_ + p * 32;
#pragma unroll
                for (int h = 0; h < 2; h++) {
                    const int f = q + 8 * h;
                    float4 a = ra[p][h];
                    bf16x4 c4;
                    c4[0] = (__bf16)a.x; c4[1] = (__bf16)a.y;
                    c4[2] = (__bf16)a.z; c4[3] = (__bf16)a.w;
                    *reinterpret_cast<bf16x4*>(
                        Aw + row * 128 + (((f >> 1) ^ (row & 7)) << 4) + (f & 1) * 8) = c4;
                }
            }
            // issue B(kt+1) first, then ra(kt+2): waits on B leave ra outstanding
#pragma unroll
            for (int n = 0; n < 4; n++)
#pragma unroll
                for (int s = 0; s < 2; s++)
                    bB[n][s] = *reinterpret_cast<const bf16x8*>(
                        bbase + n * 8192 + (kt + 1) * 1024 + s * 512);
            if (kt < 6) {
#pragma unroll
                for (int p = 0; p < 4; p++) {
                    ra[p][0] = *reinterpret_cast<const float4*>(ap[p] + (kt + 2) * 64);
                    ra[p][1] = *reinterpret_cast<const float4*>(ap[p] + (kt + 2) * 64 + 32);
                }
            }
        }
    }

    // epilogue: C/D col = l15, row = lhi*4 + j; 64B segments per 16-lane group
    const int colb = tn * 128 + wc * 64;
#pragma unroll
    for (int m = 0; m < 4; m++) {
        const int rl_ = wr * 64 + m * 16 + lhi * 4;
#pragma unroll
        for (int j = 0; j < 4; j++) {
            const int pos = tm * 128 + rl_ + j;
            if (pos < nmask) {
                const long rg = rlist[rl_ + j];
                float* orow = out + rg * DIMK + colb;
#pragma unroll
                for (int n = 0; n < 4; n++)
                    orow[n * 16 + l15] = acc[m][n][j];
            }
        }
    }
}

extern "C" void kernel_launch(void* const* d_in, const int* in_sizes, int n_in,
                              void* d_out, int out_size, void* d_ws, size_t ws_size,
                              hipStream_t stream) {
    const float* X = (const float*)d_in[0];
    const void* mask = d_in[1];
    const float* W = (const float*)d_in[2];
    float* out = (float*)d_out;
    int* mode = (int*)d_ws;

    hipLaunchKernelGGL(mask_detect, dim3(1), dim3(1024), 0, stream,
                       (const unsigned int*)mask, mode);
    hipLaunchKernelGGL(partition_kernel, dim3(NROWS / 256), dim3(256), 0, stream,
                       mask, mode);
    hipLaunchKernelGGL(wprep_kernel, dim3(64), dim3(256), 0, stream, W);
    hipLaunchKernelGGL(main_kernel, dim3(8192), dim3(256), 0, stream, X, out);
}